// Round 9
// baseline (1580.391 us; speedup 1.0000x reference)
//
#include <hip/hip_runtime.h>
#include <stdint.h>

#define B_ROWS 16384
#define NCLOUD 256
#define QDIM   2048
#define NPROMPT 1024
#define HID    64
#define ODIM   64
#define NSEL   32

typedef unsigned short u16;
typedef unsigned int u32;
typedef unsigned long long u64;
typedef __attribute__((ext_vector_type(8))) short short8;
typedef __attribute__((ext_vector_type(4))) float f32x4;

__device__ __forceinline__ u16 f2bf(float x) {
  unsigned u = __float_as_uint(x);
  unsigned r = (u + 0x7fffu + ((u >> 16) & 1u)) >> 16;  // RNE
  return (u16)r;
}
__device__ __forceinline__ float bf2f(u16 h) {
  return __uint_as_float(((unsigned)h) << 16);
}

// ---------------------------------------------------------------------------
// L2-normalize rows of [rows x 2048] f32, split into bf16 hi/lo:
// out[row][0..2047]=hi, [2048..4095]=lo. (verified R2; byte-identical to R4)
// ---------------------------------------------------------------------------
__global__ __launch_bounds__(256) void norm_split_kernel(
    const float* __restrict__ in, u16* __restrict__ out) {
  const int row = blockIdx.x;
  const int t = threadIdx.x;
  const float* rp = in + (size_t)row * QDIM;
  float4 v0 = ((const float4*)rp)[t];
  float4 v1 = ((const float4*)rp)[t + 256];
  float ss = v0.x*v0.x + v0.y*v0.y + v0.z*v0.z + v0.w*v0.w
           + v1.x*v1.x + v1.y*v1.y + v1.z*v1.z + v1.w*v1.w;
  #pragma unroll
  for (int m = 1; m < 64; m <<= 1) ss += __shfl_xor(ss, m, 64);
  __shared__ float red[4];
  if ((t & 63) == 0) red[t >> 6] = ss;
  __syncthreads();
  float tot = red[0] + red[1] + red[2] + red[3];
  float inv = 1.0f / fmaxf(sqrtf(tot), 1e-12f);
  float x0[4] = {v0.x, v0.y, v0.z, v0.w};
  float x1[4] = {v1.x, v1.y, v1.z, v1.w};
  u16 h0[4], h1[4], l0[4], l1[4];
  #pragma unroll
  for (int j = 0; j < 4; ++j) {
    float a = x0[j] * inv;
    h0[j] = f2bf(a); l0[j] = f2bf(a - bf2f(h0[j]));
    float b = x1[j] * inv;
    h1[j] = f2bf(b); l1[j] = f2bf(b - bf2f(h1[j]));
  }
  u16* ob = out + (size_t)row * (2 * QDIM);
  *(ushort4*)(ob + t * 4)               = *(const ushort4*)h0;
  *(ushort4*)(ob + 1024 + t * 4)        = *(const ushort4*)h1;
  *(ushort4*)(ob + QDIM + t * 4)        = *(const ushort4*)l0;
  *(ushort4*)(ob + QDIM + 1024 + t * 4) = *(const ushort4*)l1;
}

// ---------------------------------------------------------------------------
// P1[n][h] = sum_k prompts[n][k] * w1[h][k]  (verified R2; byte-identical)
// ---------------------------------------------------------------------------
__global__ __launch_bounds__(256) void p1_kernel(
    const float* __restrict__ prompts, const float* __restrict__ w1,
    float* __restrict__ P1) {
  const int n = blockIdx.x;
  const int wid = threadIdx.x >> 6, lane = threadIdx.x & 63;
  const float4* pr = (const float4*)(prompts + (size_t)n * 1024);
  for (int hb = 0; hb < 16; ++hb) {
    const int h = hb * 4 + wid;
    const float4* wr = (const float4*)(w1 + (size_t)h * 1024);
    float acc = 0.f;
    #pragma unroll
    for (int i = 0; i < 4; ++i) {
      float4 a = pr[i * 64 + lane];
      float4 b = wr[i * 64 + lane];
      acc += a.x * b.x + a.y * b.y + a.z * b.z + a.w * b.w;
    }
    #pragma unroll
    for (int s = 1; s < 64; s <<= 1) acc += __shfl_xor(acc, s, 64);
    if (lane == 0) P1[(size_t)n * 64 + h] = acc;
  }
}

// ---------------------------------------------------------------------------
// 256x256 8-phase split-bf16 GEMM. (byte-identical to R4 — correctness and
// absmax verified; launched x2 this round for attribution. vmcnt ledger and
// overwrite/read ordering re-audited R8: no race, no over-drain.)
// ---------------------------------------------------------------------------
#define FENCE() asm volatile("" ::: "memory")
#define BARRIER() do { FENCE(); __builtin_amdgcn_s_barrier(); FENCE(); } while (0)

__device__ __forceinline__ void stage_half(const u16* __restrict__ gbase,
                                           int grow0, int gcol0,
                                           u16* slot, int tid) {
  #pragma unroll
  for (int sel = 0; sel < 2; ++sel) {
    const int o = sel * 8192 + tid * 16;           // LDS byte offset (linear)
    const int row = o >> 7;                        // 0..127
    const int c = o & 127;
    const int cs = c ^ ((row & 7) << 4);           // inverse-swizzled source
    const u16* src = gbase + (size_t)(grow0 + row) * 4096 + gcol0 + (cs >> 1);
    __builtin_amdgcn_global_load_lds(
        (const __attribute__((address_space(1))) void*)src,
        (__attribute__((address_space(3))) void*)((char*)slot + o), 16, 0, 0);
  }
}

__device__ __forceinline__ int kcolA(int kt) {
  return ((kt >> 5) == 2 ? 2048 : 0) + (kt & 31) * 64;
}
__device__ __forceinline__ int kcolB(int kt) {
  return ((kt >> 5) == 1 ? 2048 : 0) + (kt & 31) * 64;
}

__global__ __launch_bounds__(512, 2) void gemm8p_kernel(
    const u16* __restrict__ A, const u16* __restrict__ B,
    float* __restrict__ S) {
  __shared__ u16 sH[8][8192];

  // XCD-aware bijective swizzle (nwg = 256 = 8*32)
  const int flat = blockIdx.x;
  const int v = (flat & 7) * 32 + (flat >> 3);
  const int bn = v & 3, bm = v >> 2;
  const int m0 = bm * 256, n0 = bn * 256;

  const int tid = threadIdx.x;
  const int lane = tid & 63, w = tid >> 6;
  const int wm = w >> 2, wn = w & 3;
  const int l15 = lane & 15, l16 = lane >> 4;
  const int axor = (l15 & 7) << 4;                 // swizzle XOR (bytes)
  const int acol0 = ((0 * 64 + l16 * 16) ^ axor) >> 1;   // ks=0 fragment
  const int acol1 = ((1 * 64 + l16 * 16) ^ axor) >> 1;   // ks=1 fragment
  const int arow = l15 * 64;                        // u16 units (row = l15)
  const int bbase = ((wn & 1) * 64 + l15) * 64;

  f32x4 acc[8][4] = {};

  // ---- prologue: stage A(0), B(0), B(1); drain to 4 (B(1) stays in flight)
  stage_half(A, m0 + 0 * 128, kcolA(0), sH[0], tid);
  stage_half(A, m0 + 1 * 128, kcolA(0), sH[1], tid);
  stage_half(B, n0 + 0 * 128, kcolB(0), sH[4], tid);
  stage_half(B, n0 + 1 * 128, kcolB(0), sH[5], tid);
  stage_half(B, n0 + 0 * 128, kcolB(1), sH[6], tid);
  stage_half(B, n0 + 1 * 128, kcolB(1), sH[7], tid);
  asm volatile("s_waitcnt vmcnt(4)" ::: "memory");
  BARRIER();

  for (int i = 0; i < 48; ++i) {
    const int t1 = 2 * i + 1;
    const int kA1 = kcolA(t1);
    const int kB2 = kcolB(min(2 * i + 2, 95));
    const int kA2 = kcolA(min(2 * i + 2, 95));
    const int kB3 = kcolB(min(2 * i + 3, 95));

    #pragma unroll
    for (int blk = 0; blk < 2; ++blk) {            // blk 0: tile t0/buf0, 1: t1/buf1
      const u16* aslot = sH[blk * 2 + wm];
      const u16* bslot = sH[4 + blk * 2 + (wn >> 1)];
      short8 bF[4][2];
      #pragma unroll
      for (int q = 0; q < 4; ++q) {
        if (q == 0) {
          #pragma unroll
          for (int ni = 0; ni < 4; ++ni) {
            bF[ni][0] = *(const short8*)(bslot + bbase + ni * 1024 + acol0);
            bF[ni][1] = *(const short8*)(bslot + bbase + ni * 1024 + acol1);
          }
        }
        short8 aF[2][2];
        #pragma unroll
        for (int dm = 0; dm < 2; ++dm) {
          aF[dm][0] = *(const short8*)(aslot + (2 * q + dm) * 1024 + arow + acol0);
          aF[dm][1] = *(const short8*)(aslot + (2 * q + dm) * 1024 + arow + acol1);
        }
        if (blk == 0) {
          if (q == 0) stage_half(A, m0 + 0 * 128, kA1, sH[2], tid);
          if (q == 1) stage_half(A, m0 + 1 * 128, kA1, sH[3], tid);
          if (q == 2) stage_half(B, n0 + 0 * 128, kB2, sH[4], tid);
          if (q == 3) stage_half(B, n0 + 1 * 128, kB2, sH[5], tid);
        } else {
          if (q == 0) stage_half(A, m0 + 0 * 128, kA2, sH[0], tid);
          if (q == 1) stage_half(A, m0 + 1 * 128, kA2, sH[1], tid);
          if (q == 2) stage_half(B, n0 + 0 * 128, kB3, sH[6], tid);
          if (q == 3) stage_half(B, n0 + 1 * 128, kB3, sH[7], tid);
        }
        if (q == 3) asm volatile("s_waitcnt vmcnt(4)" ::: "memory");
        BARRIER();
        asm volatile("s_waitcnt lgkmcnt(0)" ::: "memory");
        __builtin_amdgcn_sched_barrier(0);
        __builtin_amdgcn_s_setprio(1);
        #pragma unroll
        for (int ni = 0; ni < 4; ++ni)
          #pragma unroll
          for (int s = 0; s < 2; ++s) {
            acc[2 * q][ni] = __builtin_amdgcn_mfma_f32_16x16x32_bf16(
                aF[0][s], bF[ni][s], acc[2 * q][ni], 0, 0, 0);
            acc[2 * q + 1][ni] = __builtin_amdgcn_mfma_f32_16x16x32_bf16(
                aF[1][s], bF[ni][s], acc[2 * q + 1][ni], 0, 0, 0);
          }
        __builtin_amdgcn_s_setprio(0);
        BARRIER();
      }
    }
  }
  asm volatile("s_waitcnt vmcnt(0)" ::: "memory");

  const int crow0 = m0 + wm * 128 + l16 * 4;
  const int ccol0 = n0 + wn * 64 + l15;
  #pragma unroll
  for (int mi = 0; mi < 8; ++mi)
    #pragma unroll
    for (int ni = 0; ni < 4; ++ni)
      #pragma unroll
      for (int r = 0; r < 4; ++r)
        S[(size_t)(crow0 + mi * 16 + r) * 1024 + ccol0 + ni * 16] =
            0.5f - 0.5f * acc[mi][ni][r];
}

// ---------------------------------------------------------------------------
// Sort-free top-32 + softmax + MLP + broadcast. (byte-identical to R4)
// ---------------------------------------------------------------------------
__global__ __launch_bounds__(256) void topk_mlp_bcast_kernel(
    const float* __restrict__ S, const float* __restrict__ P1,
    const float* __restrict__ b1, const float* __restrict__ w2,
    const float* __restrict__ b2, float* __restrict__ xout,
    float* __restrict__ sdout) {
  const int wid = threadIdx.x >> 6;
  const int lane = threadIdx.x & 63;
  const int b = blockIdx.x * 4 + wid;

  const float* Sr = S + (size_t)b * NPROMPT;
  u32 vkey[16];
  #pragma unroll
  for (int i = 0; i < 4; ++i) {
    float4 vv = ((const float4*)Sr)[i * 64 + lane];
    float f[4] = {vv.x, vv.y, vv.z, vv.w};
    #pragma unroll
    for (int j = 0; j < 4; ++j) {
      u32 u = __float_as_uint(f[j]);
      vkey[i * 4 + j] = (u & 0x80000000u) ? ~u : (u | 0x80000000u);
    }
  }
  const u32 ib = (u32)lane * 4u;

  float seld = 0.f;
  int selidx = 0;
  for (int r = 0; r < NSEL; ++r) {
    u32 lm = vkey[0];
    #pragma unroll
    for (int s = 1; s < 16; ++s) lm = min(lm, vkey[s]);
    u32 g = lm;
    #pragma unroll
    for (int m = 1; m < 64; m <<= 1) g = min(g, (u32)__shfl_xor((int)g, m, 64));
    u32 li = 0xFFFFFFFFu;
    #pragma unroll
    for (int s = 15; s >= 0; --s)
      li = (vkey[s] == g) ? ((u32)(s >> 2) * 256u + ib + (u32)(s & 3)) : li;
    u32 gi = li;
    #pragma unroll
    for (int m = 1; m < 64; m <<= 1) gi = min(gi, (u32)__shfl_xor((int)gi, m, 64));
    if ((lane & 31) == r) {
      u32 bits = (g & 0x80000000u) ? (g ^ 0x80000000u) : ~g;
      seld = __uint_as_float(bits);
      selidx = (int)gi;
    }
    #pragma unroll
    for (int s = 0; s < 16; ++s) {
      u32 myidx = (u32)(s >> 2) * 256u + ib + (u32)(s & 3);
      if (vkey[s] == g && myidx == gi) vkey[s] = 0xFFFFFFFFu;
    }
  }

  if (lane < NSEL) sdout[(size_t)b * NSEL + lane] = seld;

  float d0 = __shfl(seld, 0, 32);
  float e = __expf(d0 - seld);
  float sum = e;
  #pragma unroll
  for (int s = 1; s < 32; s <<= 1) sum += __shfl_xor(sum, s, 32);
  float score = e / sum;

  float acc = 0.f;
  #pragma unroll
  for (int r = 0; r < NSEL; ++r) {
    float sr = __shfl(score, r, 32);
    int ir = __shfl(selidx, r, 32);
    acc = fmaf(sr, P1[(size_t)ir * HID + lane], acc);
  }
  float h = fmaxf(acc * (1.0f / NSEL) + b1[lane], 0.0f);

  float o = b2[lane];
  #pragma unroll
  for (int hh = 0; hh < 64; ++hh)
    o = fmaf(__shfl(h, hh, 64), w2[lane * HID + hh], o);

  const int src = (lane & 15) * 4;
  float4 f;
  f.x = __shfl(o, src + 0, 64);
  f.y = __shfl(o, src + 1, 64);
  f.z = __shfl(o, src + 2, 64);
  f.w = __shfl(o, src + 3, 64);
  float4* xr = (float4*)(xout + (size_t)b * (NCLOUD * ODIM));
  #pragma unroll 4
  for (int i = 0; i < 64; ++i) xr[i * 64 + lane] = f;
}

// ---------------------------------------------------------------------------
// ATTRIBUTION ROUND (4th submit — R5-R8 all infra failures, no data):
// gemm launched x2 (idempotent), all else single, byte-identical to R4.
// R9_dur - R4_dur = gemm time exactly.
// ---------------------------------------------------------------------------
extern "C" void kernel_launch(void* const* d_in, const int* in_sizes, int n_in,
                              void* d_out, int out_size, void* d_ws, size_t ws_size,
                              hipStream_t stream) {
  const float* query   = (const float*)d_in[1];
  const float* keys    = (const float*)d_in[2];
  const float* prompts = (const float*)d_in[3];
  const float* w1      = (const float*)d_in[4];
  const float* b1      = (const float*)d_in[5];
  const float* w2      = (const float*)d_in[6];
  const float* b2      = (const float*)d_in[7];

  char* ws = (char*)d_ws;
  u16*   Abig = (u16*)ws;                                       // 134217728 B
  u16*   Bbig = (u16*)(ws + 134217728);                         //   8388608 B
  float* P1   = (float*)(ws + 134217728 + 8388608);             //    262144 B
  float* S    = (float*)(ws + 134217728 + 8388608 + 262144);    //  67108864 B

  float* xout  = (float*)d_out;
  float* sdout = (float*)d_out + (size_t)B_ROWS * NCLOUD * ODIM;

  norm_split_kernel<<<B_ROWS, 256, 0, stream>>>(query, Abig);
  norm_split_kernel<<<NPROMPT, 256, 0, stream>>>(keys, Bbig);
  p1_kernel<<<NPROMPT, 256, 0, stream>>>(prompts, w1, P1);
  gemm8p_kernel<<<256, 512, 0, stream>>>(Abig, Bbig, S);
  gemm8p_kernel<<<256, 512, 0, stream>>>(Abig, Bbig, S);   // dup (attribution)
  topk_mlp_bcast_kernel<<<B_ROWS / 4, 256, 0, stream>>>(S, P1, b1, w2, b2, xout, sdout);
}

// Round 10
// 1400.075 us; speedup vs baseline: 1.1288x; 1.1288x over previous
//
#include <hip/hip_runtime.h>
#include <stdint.h>

#define B_ROWS 16384
#define NCLOUD 256
#define QDIM   2048
#define NPROMPT 1024
#define HID    64
#define ODIM   64
#define NSEL   32

typedef unsigned short u16;
typedef unsigned int u32;
typedef unsigned long long u64;
typedef __attribute__((ext_vector_type(8))) short short8;
typedef __attribute__((ext_vector_type(4))) float f32x4;

__device__ __forceinline__ u16 f2bf(float x) {
  unsigned u = __float_as_uint(x);
  unsigned r = (u + 0x7fffu + ((u >> 16) & 1u)) >> 16;  // RNE
  return (u16)r;
}
__device__ __forceinline__ float bf2f(u16 h) {
  return __uint_as_float(((unsigned)h) << 16);
}

// ---------------------------------------------------------------------------
// L2-normalize rows of [rows x 2048] f32, split into bf16 hi/lo:
// out[row][0..2047]=hi, [2048..4095]=lo. (verified R2; byte-identical to R4)
// ---------------------------------------------------------------------------
__global__ __launch_bounds__(256) void norm_split_kernel(
    const float* __restrict__ in, u16* __restrict__ out) {
  const int row = blockIdx.x;
  const int t = threadIdx.x;
  const float* rp = in + (size_t)row * QDIM;
  float4 v0 = ((const float4*)rp)[t];
  float4 v1 = ((const float4*)rp)[t + 256];
  float ss = v0.x*v0.x + v0.y*v0.y + v0.z*v0.z + v0.w*v0.w
           + v1.x*v1.x + v1.y*v1.y + v1.z*v1.z + v1.w*v1.w;
  #pragma unroll
  for (int m = 1; m < 64; m <<= 1) ss += __shfl_xor(ss, m, 64);
  __shared__ float red[4];
  if ((t & 63) == 0) red[t >> 6] = ss;
  __syncthreads();
  float tot = red[0] + red[1] + red[2] + red[3];
  float inv = 1.0f / fmaxf(sqrtf(tot), 1e-12f);
  float x0[4] = {v0.x, v0.y, v0.z, v0.w};
  float x1[4] = {v1.x, v1.y, v1.z, v1.w};
  u16 h0[4], h1[4], l0[4], l1[4];
  #pragma unroll
  for (int j = 0; j < 4; ++j) {
    float a = x0[j] * inv;
    h0[j] = f2bf(a); l0[j] = f2bf(a - bf2f(h0[j]));
    float b = x1[j] * inv;
    h1[j] = f2bf(b); l1[j] = f2bf(b - bf2f(h1[j]));
  }
  u16* ob = out + (size_t)row * (2 * QDIM);
  *(ushort4*)(ob + t * 4)               = *(const ushort4*)h0;
  *(ushort4*)(ob + 1024 + t * 4)        = *(const ushort4*)h1;
  *(ushort4*)(ob + QDIM + t * 4)        = *(const ushort4*)l0;
  *(ushort4*)(ob + QDIM + 1024 + t * 4) = *(const ushort4*)l1;
}

// ---------------------------------------------------------------------------
// P1[n][h] = sum_k prompts[n][k] * w1[h][k]  (verified R2; byte-identical)
// ---------------------------------------------------------------------------
__global__ __launch_bounds__(256) void p1_kernel(
    const float* __restrict__ prompts, const float* __restrict__ w1,
    float* __restrict__ P1) {
  const int n = blockIdx.x;
  const int wid = threadIdx.x >> 6, lane = threadIdx.x & 63;
  const float4* pr = (const float4*)(prompts + (size_t)n * 1024);
  for (int hb = 0; hb < 16; ++hb) {
    const int h = hb * 4 + wid;
    const float4* wr = (const float4*)(w1 + (size_t)h * 1024);
    float acc = 0.f;
    #pragma unroll
    for (int i = 0; i < 4; ++i) {
      float4 a = pr[i * 64 + lane];
      float4 b = wr[i * 64 + lane];
      acc += a.x * b.x + a.y * b.y + a.z * b.z + a.w * b.w;
    }
    #pragma unroll
    for (int s = 1; s < 64; s <<= 1) acc += __shfl_xor(acc, s, 64);
    if (lane == 0) P1[(size_t)n * 64 + h] = acc;
  }
}

// ---------------------------------------------------------------------------
// 256x256 8-phase split-bf16 GEMM. (byte-identical to R4/R9 — measured
// 169 us in R9 attribution, ~1.22 PF effective. Leave alone.)
// ---------------------------------------------------------------------------
#define FENCE() asm volatile("" ::: "memory")
#define BARRIER() do { FENCE(); __builtin_amdgcn_s_barrier(); FENCE(); } while (0)

__device__ __forceinline__ void stage_half(const u16* __restrict__ gbase,
                                           int grow0, int gcol0,
                                           u16* slot, int tid) {
  #pragma unroll
  for (int sel = 0; sel < 2; ++sel) {
    const int o = sel * 8192 + tid * 16;           // LDS byte offset (linear)
    const int row = o >> 7;                        // 0..127
    const int c = o & 127;
    const int cs = c ^ ((row & 7) << 4);           // inverse-swizzled source
    const u16* src = gbase + (size_t)(grow0 + row) * 4096 + gcol0 + (cs >> 1);
    __builtin_amdgcn_global_load_lds(
        (const __attribute__((address_space(1))) void*)src,
        (__attribute__((address_space(3))) void*)((char*)slot + o), 16, 0, 0);
  }
}

__device__ __forceinline__ int kcolA(int kt) {
  return ((kt >> 5) == 2 ? 2048 : 0) + (kt & 31) * 64;
}
__device__ __forceinline__ int kcolB(int kt) {
  return ((kt >> 5) == 1 ? 2048 : 0) + (kt & 31) * 64;
}

__global__ __launch_bounds__(512, 2) void gemm8p_kernel(
    const u16* __restrict__ A, const u16* __restrict__ B,
    float* __restrict__ S) {
  __shared__ u16 sH[8][8192];

  // XCD-aware bijective swizzle (nwg = 256 = 8*32)
  const int flat = blockIdx.x;
  const int v = (flat & 7) * 32 + (flat >> 3);
  const int bn = v & 3, bm = v >> 2;
  const int m0 = bm * 256, n0 = bn * 256;

  const int tid = threadIdx.x;
  const int lane = tid & 63, w = tid >> 6;
  const int wm = w >> 2, wn = w & 3;
  const int l15 = lane & 15, l16 = lane >> 4;
  const int axor = (l15 & 7) << 4;                 // swizzle XOR (bytes)
  const int acol0 = ((0 * 64 + l16 * 16) ^ axor) >> 1;   // ks=0 fragment
  const int acol1 = ((1 * 64 + l16 * 16) ^ axor) >> 1;   // ks=1 fragment
  const int arow = l15 * 64;                        // u16 units (row = l15)
  const int bbase = ((wn & 1) * 64 + l15) * 64;

  f32x4 acc[8][4] = {};

  // ---- prologue: stage A(0), B(0), B(1); drain to 4 (B(1) stays in flight)
  stage_half(A, m0 + 0 * 128, kcolA(0), sH[0], tid);
  stage_half(A, m0 + 1 * 128, kcolA(0), sH[1], tid);
  stage_half(B, n0 + 0 * 128, kcolB(0), sH[4], tid);
  stage_half(B, n0 + 1 * 128, kcolB(0), sH[5], tid);
  stage_half(B, n0 + 0 * 128, kcolB(1), sH[6], tid);
  stage_half(B, n0 + 1 * 128, kcolB(1), sH[7], tid);
  asm volatile("s_waitcnt vmcnt(4)" ::: "memory");
  BARRIER();

  for (int i = 0; i < 48; ++i) {
    const int t1 = 2 * i + 1;
    const int kA1 = kcolA(t1);
    const int kB2 = kcolB(min(2 * i + 2, 95));
    const int kA2 = kcolA(min(2 * i + 2, 95));
    const int kB3 = kcolB(min(2 * i + 3, 95));

    #pragma unroll
    for (int blk = 0; blk < 2; ++blk) {            // blk 0: tile t0/buf0, 1: t1/buf1
      const u16* aslot = sH[blk * 2 + wm];
      const u16* bslot = sH[4 + blk * 2 + (wn >> 1)];
      short8 bF[4][2];
      #pragma unroll
      for (int q = 0; q < 4; ++q) {
        if (q == 0) {
          #pragma unroll
          for (int ni = 0; ni < 4; ++ni) {
            bF[ni][0] = *(const short8*)(bslot + bbase + ni * 1024 + acol0);
            bF[ni][1] = *(const short8*)(bslot + bbase + ni * 1024 + acol1);
          }
        }
        short8 aF[2][2];
        #pragma unroll
        for (int dm = 0; dm < 2; ++dm) {
          aF[dm][0] = *(const short8*)(aslot + (2 * q + dm) * 1024 + arow + acol0);
          aF[dm][1] = *(const short8*)(aslot + (2 * q + dm) * 1024 + arow + acol1);
        }
        if (blk == 0) {
          if (q == 0) stage_half(A, m0 + 0 * 128, kA1, sH[2], tid);
          if (q == 1) stage_half(A, m0 + 1 * 128, kA1, sH[3], tid);
          if (q == 2) stage_half(B, n0 + 0 * 128, kB2, sH[4], tid);
          if (q == 3) stage_half(B, n0 + 1 * 128, kB2, sH[5], tid);
        } else {
          if (q == 0) stage_half(A, m0 + 0 * 128, kA2, sH[0], tid);
          if (q == 1) stage_half(A, m0 + 1 * 128, kA2, sH[1], tid);
          if (q == 2) stage_half(B, n0 + 0 * 128, kB3, sH[6], tid);
          if (q == 3) stage_half(B, n0 + 1 * 128, kB3, sH[7], tid);
        }
        if (q == 3) asm volatile("s_waitcnt vmcnt(4)" ::: "memory");
        BARRIER();
        asm volatile("s_waitcnt lgkmcnt(0)" ::: "memory");
        __builtin_amdgcn_sched_barrier(0);
        __builtin_amdgcn_s_setprio(1);
        #pragma unroll
        for (int ni = 0; ni < 4; ++ni)
          #pragma unroll
          for (int s = 0; s < 2; ++s) {
            acc[2 * q][ni] = __builtin_amdgcn_mfma_f32_16x16x32_bf16(
                aF[0][s], bF[ni][s], acc[2 * q][ni], 0, 0, 0);
            acc[2 * q + 1][ni] = __builtin_amdgcn_mfma_f32_16x16x32_bf16(
                aF[1][s], bF[ni][s], acc[2 * q + 1][ni], 0, 0, 0);
          }
        __builtin_amdgcn_s_setprio(0);
        BARRIER();
      }
    }
  }
  asm volatile("s_waitcnt vmcnt(0)" ::: "memory");

  const int crow0 = m0 + wm * 128 + l16 * 4;
  const int ccol0 = n0 + wn * 64 + l15;
  #pragma unroll
  for (int mi = 0; mi < 8; ++mi)
    #pragma unroll
    for (int ni = 0; ni < 4; ++ni)
      #pragma unroll
      for (int r = 0; r < 4; ++r)
        S[(size_t)(crow0 + mi * 16 + r) * 1024 + ccol0 + ni * 16] =
            0.5f - 0.5f * acc[mi][ni][r];
}

// ---------------------------------------------------------------------------
// Wave64 min-reduce via DPP (no DS-pipe traffic): row_shr 1/2/4/8 min-chain,
// row_bcast15 (0x142), row_bcast31 (0x143), result in lane 63 -> readlane.
// old = current value => invalid/disabled source lanes keep self (min identity).
// ---------------------------------------------------------------------------
__device__ __forceinline__ u32 wave_min_dpp(u32 x) {
  u32 m = x, t;
  t = (u32)__builtin_amdgcn_update_dpp((int)m, (int)m, 0x111, 0xF, 0xF, false);  // row_shr:1
  m = min(m, t);
  t = (u32)__builtin_amdgcn_update_dpp((int)m, (int)m, 0x112, 0xF, 0xF, false);  // row_shr:2
  m = min(m, t);
  t = (u32)__builtin_amdgcn_update_dpp((int)m, (int)m, 0x114, 0xF, 0xF, false);  // row_shr:4
  m = min(m, t);
  t = (u32)__builtin_amdgcn_update_dpp((int)m, (int)m, 0x118, 0xF, 0xF, false);  // row_shr:8
  m = min(m, t);
  t = (u32)__builtin_amdgcn_update_dpp((int)m, (int)m, 0x142, 0xF, 0xF, false);  // row_bcast15
  m = min(m, t);
  t = (u32)__builtin_amdgcn_update_dpp((int)m, (int)m, 0x143, 0xF, 0xF, false);  // row_bcast31
  m = min(m, t);
  return (u32)__builtin_amdgcn_readlane((int)m, 63);   // uniform (SGPR)
}

// ---------------------------------------------------------------------------
// Sort-free top-32 + softmax + MLP + broadcast. One wave per row. Same
// algorithm/tie-break as R4 (bit-identical output); the two per-round wave
// reduces now use DPP+readlane instead of 12 ds-shfl ops — selection moves
// off the DS pipe so it hides under the HBM-bound broadcast write.
// ---------------------------------------------------------------------------
__global__ __launch_bounds__(256) void topk_mlp_bcast_kernel(
    const float* __restrict__ S, const float* __restrict__ P1,
    const float* __restrict__ b1, const float* __restrict__ w2,
    const float* __restrict__ b2, float* __restrict__ xout,
    float* __restrict__ sdout) {
  const int wid = threadIdx.x >> 6;
  const int lane = threadIdx.x & 63;
  const int b = blockIdx.x * 4 + wid;

  const float* Sr = S + (size_t)b * NPROMPT;
  u32 vkey[16];
  #pragma unroll
  for (int i = 0; i < 4; ++i) {
    float4 vv = ((const float4*)Sr)[i * 64 + lane];
    float f[4] = {vv.x, vv.y, vv.z, vv.w};
    #pragma unroll
    for (int j = 0; j < 4; ++j) {
      u32 u = __float_as_uint(f[j]);
      vkey[i * 4 + j] = (u & 0x80000000u) ? ~u : (u | 0x80000000u);
    }
  }
  const u32 ib = (u32)lane * 4u;

  float seld = 0.f;
  int selidx = 0;
  for (int r = 0; r < NSEL; ++r) {
    u32 lm = vkey[0];
    #pragma unroll
    for (int s = 1; s < 16; ++s) lm = min(lm, vkey[s]);
    const u32 g = wave_min_dpp(lm);                      // global min (uniform)
    // lowest idx among this lane's matches (descending overwrite)
    u32 li = 0xFFFFFFFFu;
    #pragma unroll
    for (int s = 15; s >= 0; --s)
      li = (vkey[s] == g) ? ((u32)(s >> 2) * 256u + ib + (u32)(s & 3)) : li;
    const u32 gi = wave_min_dpp(li);                     // winning idx (uniform)
    if ((lane & 31) == r) {
      u32 bits = (g & 0x80000000u) ? (g ^ 0x80000000u) : ~g;
      seld = __uint_as_float(bits);
      selidx = (int)gi;
    }
    // invalidate the unique winner slot
    #pragma unroll
    for (int s = 0; s < 16; ++s) {
      u32 myidx = (u32)(s >> 2) * 256u + ib + (u32)(s & 3);
      if (vkey[s] == g && myidx == gi) vkey[s] = 0xFFFFFFFFu;
    }
  }

  if (lane < NSEL) sdout[(size_t)b * NSEL + lane] = seld;

  // softmax(1 - d) over 32 selected (max at smallest dist)
  float d0 = __shfl(seld, 0, 32);
  float e = __expf(d0 - seld);
  float sum = e;
  #pragma unroll
  for (int s = 1; s < 32; s <<= 1) sum += __shfl_xor(sum, s, 32);
  float score = e / sum;

  // h[lane] = relu((1/32) sum_r score_r * P1[idx_r][lane] + b1[lane])
  float acc = 0.f;
  #pragma unroll
  for (int r = 0; r < NSEL; ++r) {
    float sr = __shfl(score, r, 32);
    int ir = __shfl(selidx, r, 32);
    acc = fmaf(sr, P1[(size_t)ir * HID + lane], acc);
  }
  float h = fmaxf(acc * (1.0f / NSEL) + b1[lane], 0.0f);

  // o[lane] = b2[lane] + sum_hh h[hh] * w2[lane][hh]
  float o = b2[lane];
  #pragma unroll
  for (int hh = 0; hh < 64; ++hh)
    o = fmaf(__shfl(h, hh, 64), w2[lane * HID + hh], o);

  // broadcast o over 256 cloud points
  const int src = (lane & 15) * 4;
  float4 f;
  f.x = __shfl(o, src + 0, 64);
  f.y = __shfl(o, src + 1, 64);
  f.z = __shfl(o, src + 2, 64);
  f.w = __shfl(o, src + 3, 64);
  float4* xr = (float4*)(xout + (size_t)b * (NCLOUD * ODIM));
  #pragma unroll 4
  for (int i = 0; i < 64; ++i) xr[i * 64 + lane] = f;
}

// ---------------------------------------------------------------------------
extern "C" void kernel_launch(void* const* d_in, const int* in_sizes, int n_in,
                              void* d_out, int out_size, void* d_ws, size_t ws_size,
                              hipStream_t stream) {
  const float* query   = (const float*)d_in[1];
  const float* keys    = (const float*)d_in[2];
  const float* prompts = (const float*)d_in[3];
  const float* w1      = (const float*)d_in[4];
  const float* b1      = (const float*)d_in[5];
  const float* w2      = (const float*)d_in[6];
  const float* b2      = (const float*)d_in[7];

  char* ws = (char*)d_ws;
  u16*   Abig = (u16*)ws;                                       // 134217728 B
  u16*   Bbig = (u16*)(ws + 134217728);                         //   8388608 B
  float* P1   = (float*)(ws + 134217728 + 8388608);             //    262144 B
  float* S    = (float*)(ws + 134217728 + 8388608 + 262144);    //  67108864 B

  float* xout  = (float*)d_out;
  float* sdout = (float*)d_out + (size_t)B_ROWS * NCLOUD * ODIM;

  norm_split_kernel<<<B_ROWS, 256, 0, stream>>>(query, Abig);
  norm_split_kernel<<<NPROMPT, 256, 0, stream>>>(keys, Bbig);
  p1_kernel<<<NPROMPT, 256, 0, stream>>>(prompts, w1, P1);
  gemm8p_kernel<<<256, 512, 0, stream>>>(Abig, Bbig, S);
  topk_mlp_bcast_kernel<<<B_ROWS / 4, 256, 0, stream>>>(S, P1, b1, w2, b2, xout, sdout);
}